// Round 8
// baseline (55.466 us; speedup 1.0000x reference)
//
#include <hip/hip_runtime.h>
#include <hip/hip_bf16.h>

// SpatialGATAttention — single fully-fused kernel, v6 (MI355X / gfx950)
// Round-8: drop cooperative launch (failed). Instead fuse proj INTO each attn
// block: every (m,ch) block recomputes its V-half fragments + sdst from x
// (4x redundant, MFMA/VALU-trivial; x reads L2-absorbed via XCD swizzle).
// No workspace, no grid sync, no mask_ws (gso + cndmask directly).
// Own-rows half processed FIRST so ssrc is ready before PV (un-normalized
// softmax => half order commutes). LDS 52KB -> 3 blocks/CU at grid 768.

#define NB 8
#define NC 64
#define NT 24
#define NN 512
#define LOG2E 1.44269504088896f

typedef float f32x4 __attribute__((ext_vector_type(4)));
typedef short bf16x8 __attribute__((ext_vector_type(8)));
typedef int   i32x4 __attribute__((ext_vector_type(4)));
typedef unsigned int u32;
typedef u32 u32x2 __attribute__((ext_vector_type(2)));

#ifndef __has_builtin
#define __has_builtin(x) 0
#endif

__device__ __forceinline__ float fast_exp2(float x) {
#if __has_builtin(__builtin_amdgcn_exp2f)
    return __builtin_amdgcn_exp2f(x);
#else
    return exp2f(x);
#endif
}

// hardware RNE conversions (memcpy = free register move)
__device__ __forceinline__ u32 pk_bf16(float lo, float hi) {
    __hip_bfloat162 h2 = __float22bfloat162_rn(float2{lo, hi});
    u32 r; __builtin_memcpy(&r, &h2, 4); return r;
}
__device__ __forceinline__ unsigned short f2bfh(float f) {
    __hip_bfloat16 h = __float2bfloat16(f);
    unsigned short r; __builtin_memcpy(&r, &h, 2); return r;
}
__device__ __forceinline__ float bf2f(unsigned short s) {
    union { unsigned int u; float f; } v;
    v.u = ((unsigned int)s) << 16;
    return v.f;
}

// V fragment layout within a half (u16 index): k2 = n_half>>5 (0..7)
#define VT2_IDX(k2,h,qq,dt,dl,e) \
    ((((((k2)*2+(h))*4+(qq))*2+(dt))*16+(dl))*8+(e))

// swizzled x-chunk (u16 index): row n (0..63), col c (0..63); 16B-block XOR
#define XRB64(n,c) (((n)<<6) + (((((c)>>3) ^ ((n)&7))<<3) | ((c)&7)))

// =====================================================================
// Fully fused kernel. grid 768 = (m:192) x (ch:4) XCD-swizzled, block 512.
// Per block: for each j-half (own half first):
//   4x { stage x 64-n chunk (bf16, swizzled) ; sdst(+ssrc) dots ; V MFMA }
//   then PV k-loop over the half (exp2 softmax weights in A-frag layout,
//   row-sums via ones-MFMA). Epilogue: normalize + LayerNorm + store.
// =====================================================================
__global__ __launch_bounds__(512, 6)
void gat_one(const float* __restrict__ x, const int* __restrict__ gso,
             const float* __restrict__ Wq, const float* __restrict__ Wk,
             const float* __restrict__ Wv, const float* __restrict__ a_src,
             const float* __restrict__ a_dst, const float* __restrict__ gamma,
             const float* __restrict__ beta, float* __restrict__ out)
{
    __shared__ unsigned short sm_x[4096];     //  8 KB: 64n x 64c bf16 swizzled
    __shared__ unsigned short sm_v[16384];    // 32 KB: V fragments, one half
    __shared__ unsigned short sm_wvb[4096];   //  8 KB: Wv B-fragments
    __shared__ float sm_sdst[2][256];         //  2 KB: dst scores, current half
    __shared__ float sm_ssrc[2][128];         //  1 KB: src scores, own rows
    __shared__ float sm_wqa[2][NC];           // 0.5KB
    __shared__ float sm_wka[2][NC];           // 0.5KB

    const int bid  = blockIdx.x;
    // XCD swizzle: the 4 ch-blocks of one m share (bid & 7) -> same XCD L2
    const int m    = (bid >> 5) * 8 + (bid & 7);
    const int ch   = (bid >> 3) & 3;
    const int b    = m / NT;
    const int tt   = m % NT;
    const int tid  = threadIdx.x;
    const int lane = tid & 63;
    const int wid  = tid >> 6;
    const int fr   = lane & 15;
    const int fq   = lane >> 4;

    // ---- folded attention vectors (pre-scaled by log2 e) ----
    if (tid < 128) {
        const int h = tid >> 6, c = tid & 63;
        float aq = 0.f, ak = 0.f;
        #pragma unroll
        for (int d = 0; d < 32; ++d) {
            aq += Wq[(h*32 + d)*NC + c] * a_src[h*32 + d];
            ak += Wk[(h*32 + d)*NC + c] * a_dst[h*32 + d];
        }
        sm_wqa[h][c] = aq * LOG2E;
        sm_wka[h][c] = ak * LOG2E;
    }
    // ---- Wv as bf16 B-fragments ----
    for (int idx = tid; idx < 4096; idx += 512) {
        const int e   = idx & 7;
        const int dl  = (idx >> 3) & 15;
        const int dt4 = (idx >> 7) & 3;
        const int qq  = (idx >> 9) & 3;
        const int ks  = idx >> 11;
        sm_wvb[idx] = f2bfh(Wv[(dt4*16 + dl)*NC + ks*32 + qq*8 + e]);
    }
    // (first chunk's staging syncthreads covers visibility of the above)

    // ones-column B fragment (col 0 = 1.0bf16) for MFMA row-sums
    bf16x8 bones;
    {
        union { i32x4 i; bf16x8 h; } cv;
        const int w = (fr == 0) ? 0x3F803F80 : 0;
        cv.i[0] = w; cv.i[1] = w; cv.i[2] = w; cv.i[3] = w;
        bones = cv.h;
    }

    const int own_half = ch >> 1;
    const int ig = ch*128 + wid*16 + fr;          // this lane's softmax row
    float src0 = 0.f, src1 = 0.f;

    f32x4 acc[4] = {};
    f32x4 accs0 = {}, accs1 = {};

    #pragma unroll
    for (int pass = 0; pass < 2; ++pass) {
        const int hf = pass ? (1 - own_half) : own_half;   // own half FIRST

        // ======== proj sub-phase: 4 chunks of 64 n ========
        for (int cidx = 0; cidx < 4; ++cidx) {
            const int nh0 = cidx * 64;            // base n within half
            const int ng0 = hf*256 + nh0;         // global n

            __syncthreads();   // prior users of sm_x / sm_v are done

            // ---- stage x chunk: wave = c-octet, lane = n (coalesced 256B) ----
            {
                const int cb = wid * 8;
                float v[8];
                #pragma unroll
                for (int e = 0; e < 8; ++e)
                    v[e] = x[((size_t)(b*NC + cb + e)*NT + tt)*NN + ng0 + lane];
                i32x4 w;
                #pragma unroll
                for (int j = 0; j < 4; ++j)
                    w[j] = (int)pk_bf16(v[2*j], v[2*j+1]);
                *reinterpret_cast<i32x4*>(&sm_x[XRB64(lane, cb)]) = w;
            }
            __syncthreads();

            // ---- sdst (+ssrc for own rows) dots over c ----
            {
                const int nloc = tid >> 3;        // 0..63
                const int cp   = tid & 7;         // c-octet
                float sk0=0.f, sk1=0.f, sq0=0.f, sq1=0.f;
                #pragma unroll
                for (int i = 0; i < 8; ++i) {
                    const int c = cp*8 + i;
                    const float xv = bf2f(sm_x[XRB64(nloc, c)]);
                    sk0 += xv * sm_wka[0][c];
                    sk1 += xv * sm_wka[1][c];
                    sq0 += xv * sm_wqa[0][c];
                    sq1 += xv * sm_wqa[1][c];
                }
                sk0 += __shfl_xor(sk0,1); sk0 += __shfl_xor(sk0,2); sk0 += __shfl_xor(sk0,4);
                sk1 += __shfl_xor(sk1,1); sk1 += __shfl_xor(sk1,2); sk1 += __shfl_xor(sk1,4);
                sq0 += __shfl_xor(sq0,1); sq0 += __shfl_xor(sq0,2); sq0 += __shfl_xor(sq0,4);
                sq1 += __shfl_xor(sq1,1); sq1 += __shfl_xor(sq1,2); sq1 += __shfl_xor(sq1,4);
                if (cp == 0) {
                    sm_sdst[0][nh0 + nloc] = sk0;
                    sm_sdst[1][nh0 + nloc] = sk1;
                    if (pass == 0 && (cidx >> 1) == (ch & 1)) {
                        sm_ssrc[0][(cidx & 1)*64 + nloc] = sq0;
                        sm_ssrc[1][(cidx & 1)*64 + nloc] = sq1;
                    }
                }
            }

            // ---- V projection for chunk: wave -> (n-tile = wid>>1, head = wid&1) ----
            {
                const int t = wid >> 1;           // n-tile 0..3
                const int h = wid & 1;            // head
                f32x4 vacc[2] = {};
                #pragma unroll
                for (int ks = 0; ks < 2; ++ks) {
                    const bf16x8 af = *reinterpret_cast<const bf16x8*>(
                        &sm_x[XRB64(t*16 + fr, ks*32 + fq*8)]);
                    #pragma unroll
                    for (int dt = 0; dt < 2; ++dt) {
                        const int dt4 = h*2 + dt;
                        const bf16x8 bfv = *reinterpret_cast<const bf16x8*>(
                            &sm_wvb[(((ks*4 + fq)*4 + dt4)*16 + fr)*8]);
                        vacc[dt] = __builtin_amdgcn_mfma_f32_16x16x32_bf16(
                            af, bfv, vacc[dt], 0, 0, 0);
                    }
                }
                const int nh = nh0 + t*16 + 4*fq;   // n within half
                #pragma unroll
                for (int dt = 0; dt < 2; ++dt) {
                    u32x2 dd;
                    dd[0] = pk_bf16(vacc[dt][0], vacc[dt][1]);
                    dd[1] = pk_bf16(vacc[dt][2], vacc[dt][3]);
                    *reinterpret_cast<u32x2*>(
                        &sm_v[VT2_IDX(nh>>5, h, (nh>>3)&3, dt, fr, nh&7)]) = dd;
                }
            }
        }
        __syncthreads();   // V-half + sdst complete

        if (pass == 0) {
            src0 = sm_ssrc[0][wid*16 + fr];
            src1 = sm_ssrc[1][wid*16 + fr];
        }

        // ======== PV sub-phase over this half ========
        const int* gbase = &gso[(size_t)ig*NN + hf*256 + fq*8];
        for (int k2 = 0; k2 < 8; ++k2) {
            const int j0l = k2*32 + fq*8;         // within-half j offset
            const i32x4 g0 = *reinterpret_cast<const i32x4*>(gbase + k2*32);
            const i32x4 g1 = *reinterpret_cast<const i32x4*>(gbase + k2*32 + 4);
            const f32x4 da0 = *reinterpret_cast<const f32x4*>(&sm_sdst[0][j0l]);
            const f32x4 db0 = *reinterpret_cast<const f32x4*>(&sm_sdst[0][j0l+4]);
            const f32x4 da1 = *reinterpret_cast<const f32x4*>(&sm_sdst[1][j0l]);
            const f32x4 db1 = *reinterpret_cast<const f32x4*>(&sm_sdst[1][j0l+4]);

            u32 u0[8], u1[8];
            #pragma unroll
            for (int e = 0; e < 4; ++e) {
                float s0 = src0 + da0[e]; s0 = fmaxf(s0, 0.2f*s0);
                float s1 = src1 + da1[e]; s1 = fmaxf(s1, 0.2f*s1);
                const bool gb = (g0[e] != 0);      // one cmp feeds both heads
                u0[e] = gb ? __float_as_uint(fast_exp2(s0)) : 0u;
                u1[e] = gb ? __float_as_uint(fast_exp2(s1)) : 0u;
            }
            #pragma unroll
            for (int e = 0; e < 4; ++e) {
                float s0 = src0 + db0[e]; s0 = fmaxf(s0, 0.2f*s0);
                float s1 = src1 + db1[e]; s1 = fmaxf(s1, 0.2f*s1);
                const bool gb = (g1[e] != 0);
                u0[4+e] = gb ? __float_as_uint(fast_exp2(s0)) : 0u;
                u1[4+e] = gb ? __float_as_uint(fast_exp2(s1)) : 0u;
            }
            union { i32x4 i; bf16x8 h; } c0, c1;
            c0.i[0] = __builtin_amdgcn_perm(u0[1], u0[0], 0x07060302u);
            c0.i[1] = __builtin_amdgcn_perm(u0[3], u0[2], 0x07060302u);
            c0.i[2] = __builtin_amdgcn_perm(u0[5], u0[4], 0x07060302u);
            c0.i[3] = __builtin_amdgcn_perm(u0[7], u0[6], 0x07060302u);
            c1.i[0] = __builtin_amdgcn_perm(u1[1], u1[0], 0x07060302u);
            c1.i[1] = __builtin_amdgcn_perm(u1[3], u1[2], 0x07060302u);
            c1.i[2] = __builtin_amdgcn_perm(u1[5], u1[4], 0x07060302u);
            c1.i[3] = __builtin_amdgcn_perm(u1[7], u1[6], 0x07060302u);
            const bf16x8 af0 = c0.h, af1 = c1.h;

            accs0 = __builtin_amdgcn_mfma_f32_16x16x32_bf16(af0, bones, accs0, 0,0,0);
            {
                const bf16x8 b0 = *reinterpret_cast<const bf16x8*>(
                    &sm_v[VT2_IDX(k2,0,fq,0,fr,0)]);
                const bf16x8 b1 = *reinterpret_cast<const bf16x8*>(
                    &sm_v[VT2_IDX(k2,0,fq,1,fr,0)]);
                acc[0] = __builtin_amdgcn_mfma_f32_16x16x32_bf16(af0, b0, acc[0], 0,0,0);
                acc[1] = __builtin_amdgcn_mfma_f32_16x16x32_bf16(af0, b1, acc[1], 0,0,0);
            }
            accs1 = __builtin_amdgcn_mfma_f32_16x16x32_bf16(af1, bones, accs1, 0,0,0);
            {
                const bf16x8 b0 = *reinterpret_cast<const bf16x8*>(
                    &sm_v[VT2_IDX(k2,1,fq,0,fr,0)]);
                const bf16x8 b1 = *reinterpret_cast<const bf16x8*>(
                    &sm_v[VT2_IDX(k2,1,fq,1,fr,0)]);
                acc[2] = __builtin_amdgcn_mfma_f32_16x16x32_bf16(af1, b0, acc[2], 0,0,0);
                acc[3] = __builtin_amdgcn_mfma_f32_16x16x32_bf16(af1, b1, acc[3], 0,0,0);
            }
        }
        // next pass's first chunk __syncthreads guards sm_v/sm_x reuse
    }

    // ---- epilogue: normalize + LayerNorm + store (B,C,T,N) ----
    float gmv[4], btv[4];
    #pragma unroll
    for (int dt4 = 0; dt4 < 4; ++dt4) {
        gmv[dt4] = gamma[dt4*16 + fr];
        btv[dt4] = beta [dt4*16 + fr];
    }
    #pragma unroll
    for (int rg = 0; rg < 4; ++rg) {
        const int rowloc = 4*fq + rg;
        const float rs0 = __shfl(accs0[rg], lane & 48);
        const float rs1 = __shfl(accs1[rg], lane & 48);
        const float inv0 = 1.f / rs0, inv1 = 1.f / rs1;
        float vv[4];
        vv[0] = acc[0][rg] * inv0;
        vv[1] = acc[1][rg] * inv0;
        vv[2] = acc[2][rg] * inv1;
        vv[3] = acc[3][rg] * inv1;
        float sum = vv[0]+vv[1]+vv[2]+vv[3];
        float ssq = vv[0]*vv[0]+vv[1]*vv[1]+vv[2]*vv[2]+vv[3]*vv[3];
        sum += __shfl_xor(sum,1); sum += __shfl_xor(sum,2);
        sum += __shfl_xor(sum,4); sum += __shfl_xor(sum,8);
        ssq += __shfl_xor(ssq,1); ssq += __shfl_xor(ssq,2);
        ssq += __shfl_xor(ssq,4); ssq += __shfl_xor(ssq,8);
        const float mu   = sum * (1.f/64.f);
        const float var  = ssq * (1.f/64.f) - mu*mu;
        const float rstd = rsqrtf(var + 1e-5f);
        const int irow = ch*128 + wid*16 + rowloc;
        #pragma unroll
        for (int dt4 = 0; dt4 < 4; ++dt4) {
            const float o = (vv[dt4] - mu) * rstd * gmv[dt4] + btv[dt4];
            out[((size_t)(b*NC + dt4*16 + fr)*NT + tt)*NN + irow] = o;
        }
    }
}

extern "C" void kernel_launch(void* const* d_in, const int* in_sizes, int n_in,
                              void* d_out, int out_size, void* d_ws, size_t ws_size,
                              hipStream_t stream) {
    (void)in_sizes; (void)n_in; (void)out_size; (void)d_ws; (void)ws_size;
    const float* x     = (const float*)d_in[0];
    const int*   gso   = (const int*)  d_in[1];
    const float* Wq    = (const float*)d_in[2];
    const float* Wk    = (const float*)d_in[3];
    const float* Wv    = (const float*)d_in[4];
    const float* a_src = (const float*)d_in[5];
    const float* a_dst = (const float*)d_in[6];
    const float* gamma = (const float*)d_in[7];
    const float* beta  = (const float*)d_in[8];
    float* out = (float*)d_out;

    gat_one<<<768, 512, 0, stream>>>(x, gso, Wq, Wk, Wv, a_src, a_dst,
                                     gamma, beta, out);
}